// Round 3
// baseline (158.061 us; speedup 1.0000x reference)
//
#include <hip/hip_runtime.h>

#define KDIM 4096   // rows of x (= both i and j extents)
#define NDIM 1024   // feature dim
#define ALPHA 0.2f
#define LOG2E 1.4426950408889634f

typedef __attribute__((ext_vector_type(8))) short bf16x8;
typedef __attribute__((ext_vector_type(4))) float f32x4;

// Persistent device scratch. Inputs/outputs are FLOAT32 (per reference);
// internal P / xT are bf16 for MFMA (2% absmax threshold allows it).
__device__ __align__(16) unsigned short g_P [(size_t)KDIM * KDIM];  // 32 MB: unnormalized softmax numerators, bf16
__device__ __align__(16) unsigned short g_xT[(size_t)NDIM * KDIM];  //  8 MB: x^T in bf16 (n-major, j contiguous)
__device__ __align__(16) float g_s1L[KDIM];
__device__ __align__(16) float g_s2L[KDIM];
__device__ __align__(16) float g_rZ [KDIM];

__device__ __forceinline__ unsigned short f2bf(float f){
  unsigned int b = __float_as_uint(f);
  b += 0x7FFFu + ((b >> 16) & 1u);      // RNE
  return (unsigned short)(b >> 16);
}

// ---- kernel 1: s1L/s2L = (x @ w1, x @ w2) * log2(e).  One wave per row, f32 in. ----
__global__ __launch_bounds__(256) void k_dots(const float* __restrict__ x,
                                              const float* __restrict__ w){
  const int wid = threadIdx.x >> 6, lane = threadIdx.x & 63;
  const int row = blockIdx.x * 4 + wid;
  const float* xr = x + (size_t)row * NDIM;
  float d1 = 0.f, d2 = 0.f;
  #pragma unroll
  for (int q = 0; q < 4; ++q){
    const int off = q * 256 + lane * 4;          // 16B per lane, coalesced
    float4 X  = *(const float4*)(xr + off);
    float4 W1 = *(const float4*)(w + off);
    float4 W2 = *(const float4*)(w + NDIM + off);
    d1 = fmaf(X.x, W1.x, fmaf(X.y, W1.y, fmaf(X.z, W1.z, fmaf(X.w, W1.w, d1))));
    d2 = fmaf(X.x, W2.x, fmaf(X.y, W2.y, fmaf(X.z, W2.z, fmaf(X.w, W2.w, d2))));
  }
  #pragma unroll
  for (int m = 32; m >= 1; m >>= 1){
    d1 += __shfl_xor(d1, m, 64);
    d2 += __shfl_xor(d2, m, 64);
  }
  if (lane == 0){
    g_s1L[row] = d1 * LOG2E;
    g_s2L[row] = d2 * LOG2E;
  }
}

// ---- kernel 2: per-row m_i, Z_i; materialize P (bf16). One wave per row i. ----
// m_i = lrelu(s1 + max_j s2) since lrelu is strictly increasing; positive scaling
// (log2e) commutes with lrelu and max, so everything runs in log2 space.
__global__ __launch_bounds__(256) void k_prep(){
  __shared__ __align__(16) float s2[KDIM];      // 16 KB
  __shared__ float red[256];
  float mx = -3.0e38f;
  {
    int i = threadIdx.x * 4;
    #pragma unroll
    for (int c = 0; c < 4; ++c, i += 1024){
      float4 v = *(const float4*)&g_s2L[i];
      *(float4*)&s2[i] = v;
      mx = fmaxf(mx, fmaxf(fmaxf(v.x, v.y), fmaxf(v.z, v.w)));
    }
  }
  red[threadIdx.x] = mx;
  __syncthreads();
  #pragma unroll
  for (int s = 128; s >= 1; s >>= 1){
    if (threadIdx.x < s) red[threadIdx.x] = fmaxf(red[threadIdx.x], red[threadIdx.x + s]);
    __syncthreads();
  }
  const float m2 = red[0];                       // max_j s2L_j

  const int wid = threadIdx.x >> 6, lane = threadIdx.x & 63;
  const int row = blockIdx.x * 4 + wid;
  const float s1 = g_s1L[row];
  const float t  = s1 + m2;
  const float mL = fmaxf(t, ALPHA * t);          // lrelu in log2 space
  const float c1 = s1 - mL;
  const float c2 = fmaf(ALPHA, s1, -mL);
  float z = 0.f;
  unsigned short* prow = g_P + (size_t)row * KDIM;
  #pragma unroll
  for (int ch = 0; ch < 8; ++ch){
    const int j = ch * 512 + lane * 8;
    float4 a = *(const float4*)&s2[j];
    float4 b = *(const float4*)&s2[j + 4];
    float sv[8] = {a.x, a.y, a.z, a.w, b.x, b.y, b.z, b.w};
    union { uint4 u; unsigned short s[8]; } pk;
    #pragma unroll
    for (int s = 0; s < 8; ++s){
      const float arg = fmaxf(c1 + sv[s], fmaf(ALPHA, sv[s], c2)); // <= 0
      const float pv  = __builtin_amdgcn_exp2f(arg);               // (0,1]
      z += pv;
      pk.s[s] = f2bf(pv);
    }
    *(uint4*)(prow + j) = pk.u;                  // coalesced 16B stores
  }
  #pragma unroll
  for (int m = 32; m >= 1; m >>= 1) z += __shfl_xor(z, m, 64);
  if (lane == 0) g_rZ[row] = 1.0f / z;
}

// ---- kernel 3: transpose+convert x (f32, j-major) -> g_xT (bf16, n-major). ----
// 64x64 tiles; LDS rows padded to 80 shorts (160 B) so uint4 readback is 16B-aligned.
__global__ __launch_bounds__(256) void k_transpose(const float* __restrict__ x){
  __shared__ __align__(16) unsigned short T[64][80];
  const int n0 = blockIdx.x * 64, j0 = blockIdx.y * 64;
  const int tid = threadIdx.x;
  #pragma unroll
  for (int it = 0; it < 4; ++it){
    const int idx = it * 256 + tid;
    const int r = idx >> 4, c4 = idx & 15;       // row 0..63, float4-col 0..15
    float4 v = *(const float4*)(x + (size_t)(j0 + r) * NDIM + n0 + c4 * 4);
    T[c4 * 4 + 0][r] = f2bf(v.x);
    T[c4 * 4 + 1][r] = f2bf(v.y);
    T[c4 * 4 + 2][r] = f2bf(v.z);
    T[c4 * 4 + 3][r] = f2bf(v.w);
  }
  __syncthreads();
  #pragma unroll
  for (int it = 0; it < 2; ++it){
    const int idx = it * 256 + tid;
    const int n = idx >> 3, cb = idx & 7;        // col(row of xT) 0..63, uint4 0..7
    uint4 u = *(const uint4*)&T[n][cb * 8];
    *(uint4*)(g_xT + (size_t)(n0 + n) * KDIM + j0 + cb * 8) = u;
  }
}

// ---- kernel 4: h = (P @ x) * rZ, bf16 MFMA GEMM, f32 out. M=4096 N=1024 K=4096. ----
// 128x128 tile, BK=64, 512 threads (8 waves as 4x2; wave-tile 32x64 = 2x4 frags).
// Tiles staged m/n-major, 64-bf16 (128 B) rows; col-blocks XOR-swizzled by (row&7)
// so ds_read_b128 frag reads spread across banks. Double-buffered LDS, ONE barrier
// per K-iter: prefetch glds(kt+1) issued before compute(kt) so the pre-barrier
// vmcnt(0) drain overlaps a full compute phase.
__global__ __launch_bounds__(512, 2) void k_gemm(float* __restrict__ out){
  __shared__ __align__(16) unsigned short Ab[2][8192];  // 2 x 16 KB
  __shared__ __align__(16) unsigned short Bb[2][8192];
  const int tid  = threadIdx.x;
  const int w    = tid >> 6, lane = tid & 63;
  const int quad = lane >> 4, l15 = lane & 15;
  const int i0 = blockIdx.y * 128, n0 = blockIdx.x * 128;
  const int m_orig = (w >> 1) * 32, n_orig = (w & 1) * 64;
  // staging: chunk = 1 KB = 8 rows; glds lands lane L at chunk_base + L*16B,
  // so LDS[row][blk] = global[row][blk ^ (row&7)]  (XOR bank swizzle).
  const int srow = lane >> 3;                 // 0..7
  const int sblk = (lane & 7) ^ srow;

  f32x4 acc[2][4] = {};

  auto stage = [&](int kt, int buf){
    const int kbase = kt * 64;
    #pragma unroll
    for (int c = 0; c < 2; ++c){
      const int ca = (w << 1) + c;            // chunk 0..15
      const int r  = ca * 8 + srow;
      const unsigned short* ga = g_P  + (size_t)(i0 + r) * KDIM + kbase + sblk * 8;
      const unsigned short* gb = g_xT + (size_t)(n0 + r) * KDIM + kbase + sblk * 8;
      __builtin_amdgcn_global_load_lds((const __attribute__((address_space(1))) void*)ga,
          (__attribute__((address_space(3))) void*)(&Ab[buf][ca * 512]), 16, 0, 0);
      __builtin_amdgcn_global_load_lds((const __attribute__((address_space(1))) void*)gb,
          (__attribute__((address_space(3))) void*)(&Bb[buf][ca * 512]), 16, 0, 0);
    }
  };

  auto compute = [&](int buf){
    #pragma unroll
    for (int ks = 0; ks < 2; ++ks){
      const int lbq = ((ks << 2) + quad) ^ (lane & 7);   // swizzled k-block
      bf16x8 af[2], bfr[4];
      #pragma unroll
      for (int mf = 0; mf < 2; ++mf){
        const int m = m_orig + mf * 16 + l15;            // m&7 == lane&7
        af[mf] = *(const bf16x8*)((const char*)&Ab[buf][0] + m * 128 + lbq * 16);
      }
      #pragma unroll
      for (int nf = 0; nf < 4; ++nf){
        const int n = n_orig + nf * 16 + l15;
        bfr[nf] = *(const bf16x8*)((const char*)&Bb[buf][0] + n * 128 + lbq * 16);
      }
      #pragma unroll
      for (int mf = 0; mf < 2; ++mf)
        #pragma unroll
        for (int nf = 0; nf < 4; ++nf)
          acc[mf][nf] = __builtin_amdgcn_mfma_f32_16x16x32_bf16(af[mf], bfr[nf], acc[mf][nf], 0, 0, 0);
    }
  };

  stage(0, 0);
  for (int kt = 0; kt < 64; ++kt){
    __syncthreads();                       // drains this iter's staged buffer (vmcnt(0))
    if (kt + 1 < 64) stage(kt + 1, (kt + 1) & 1);   // prefetch overlaps compute below
    compute(kt & 1);
  }

  // epilogue: scale by 1/Z_i, store f32. C/D layout: col=lane&15, row=quad*4+reg.
  #pragma unroll
  for (int mf = 0; mf < 2; ++mf){
    #pragma unroll
    for (int r = 0; r < 4; ++r){
      const int row = i0 + m_orig + mf * 16 + quad * 4 + r;
      const float rz = g_rZ[row];
      #pragma unroll
      for (int nf = 0; nf < 4; ++nf){
        const int col = n0 + n_orig + nf * 16 + l15;
        out[(size_t)row * NDIM + col] = acc[mf][nf][r] * rz;
      }
    }
  }
}

extern "C" void kernel_launch(void* const* d_in, const int* in_sizes, int n_in,
                              void* d_out, int out_size, void* d_ws, size_t ws_size,
                              hipStream_t stream){
  const float* x = (const float*)d_in[0];   // f32 (4096x1024)
  const float* w = (const float*)d_in[1];   // f32 (2048)
  float* out = (float*)d_out;               // f32 (4096x1024)
  (void)in_sizes; (void)n_in; (void)out_size; (void)d_ws; (void)ws_size;

  k_dots     <<<dim3(1024),    dim3(256), 0, stream>>>(x, w);
  k_prep     <<<dim3(1024),    dim3(256), 0, stream>>>();
  k_transpose<<<dim3(16, 64),  dim3(256), 0, stream>>>(x);
  k_gemm     <<<dim3(8, 32),   dim3(512), 0, stream>>>(out);
}

// Round 5
// 149.327 us; speedup vs baseline: 1.0585x; 1.0585x over previous
//
#include <hip/hip_runtime.h>

#define KDIM 4096   // rows of x (= both i and j extents)
#define NDIM 1024   // feature dim
#define ALPHA 0.2f
#define LOG2E 1.4426950408889634f

typedef __fp16   fp16x2 __attribute__((ext_vector_type(2)));   // cvt_pkrtz result type
typedef _Float16 f16x8  __attribute__((ext_vector_type(8)));   // MFMA operand type
typedef __attribute__((ext_vector_type(4))) float f32x4;

// Persistent device scratch. Inputs/outputs are FLOAT32; internals f16/f32.
// P is NEVER materialized: P_ij = sel ? E1_j*F1_i : E2_j*F2_i with
// sel = (s2_j >= -s1_i)  <=>  (E1_j >= G_i), G_i = exp2(-s1L_i).
__device__ __align__(16) unsigned short g_xT[(size_t)NDIM * KDIM]; // 8 MB: x^T, f16 bits (n-major, j contiguous)
__device__ __align__(16) float g_s1L[KDIM];
__device__ __align__(16) float g_s2L[KDIM];
__device__ __align__(16) float g_E [2 * KDIM];   // interleaved (E1_j, E2_j)
__device__ __align__(16) float g_G [KDIM];
__device__ __align__(16) float g_F1[KDIM];
__device__ __align__(16) float g_F2[KDIM];
__device__ __align__(16) float g_rZ[KDIM];

__device__ __forceinline__ unsigned short f2h(float f){
  _Float16 h = (_Float16)f;
  return *(unsigned short*)&h;
}

// ---- kernel 1: s1L/s2L = (x @ w1, x @ w2) * log2(e).  One wave per row. ----
__global__ __launch_bounds__(256) void k_dots(const float* __restrict__ x,
                                              const float* __restrict__ w){
  const int wid = threadIdx.x >> 6, lane = threadIdx.x & 63;
  const int row = blockIdx.x * 4 + wid;
  const float* xr = x + (size_t)row * NDIM;
  float d1 = 0.f, d2 = 0.f;
  #pragma unroll
  for (int q = 0; q < 4; ++q){
    const int off = q * 256 + lane * 4;
    float4 X  = *(const float4*)(xr + off);
    float4 W1 = *(const float4*)(w + off);
    float4 W2 = *(const float4*)(w + NDIM + off);
    d1 = fmaf(X.x, W1.x, fmaf(X.y, W1.y, fmaf(X.z, W1.z, fmaf(X.w, W1.w, d1))));
    d2 = fmaf(X.x, W2.x, fmaf(X.y, W2.y, fmaf(X.z, W2.z, fmaf(X.w, W2.w, d2))));
  }
  #pragma unroll
  for (int m = 32; m >= 1; m >>= 1){
    d1 += __shfl_xor(d1, m, 64);
    d2 += __shfl_xor(d2, m, 64);
  }
  if (lane == 0){
    g_s1L[row] = d1 * LOG2E;
    g_s2L[row] = d2 * LOG2E;
  }
}

// ---- kernel 2: m2 = max_j s2L; E1/E2 per j; F1/F2/G per i. One block. ----
// mL_i = lrelu(s1L + m2) (lrelu commutes with positive scaling & max).
__global__ __launch_bounds__(1024) void k_escan(){
  __shared__ float red[1024];
  const int tid = threadIdx.x;
  const float4 s2v = *(const float4*)&g_s2L[tid * 4];
  red[tid] = fmaxf(fmaxf(s2v.x, s2v.y), fmaxf(s2v.z, s2v.w));
  __syncthreads();
  #pragma unroll
  for (int s = 512; s >= 1; s >>= 1){
    if (tid < s) red[tid] = fmaxf(red[tid], red[tid + s]);
    __syncthreads();
  }
  const float m2 = red[0];

  float4 e0, e1;
  e0.x = __builtin_amdgcn_exp2f(s2v.x); e0.y = __builtin_amdgcn_exp2f(ALPHA * s2v.x);
  e0.z = __builtin_amdgcn_exp2f(s2v.y); e0.w = __builtin_amdgcn_exp2f(ALPHA * s2v.y);
  e1.x = __builtin_amdgcn_exp2f(s2v.z); e1.y = __builtin_amdgcn_exp2f(ALPHA * s2v.z);
  e1.z = __builtin_amdgcn_exp2f(s2v.w); e1.w = __builtin_amdgcn_exp2f(ALPHA * s2v.w);
  *(float4*)&g_E[tid * 8]     = e0;
  *(float4*)&g_E[tid * 8 + 4] = e1;

  const float4 s1v = *(const float4*)&g_s1L[tid * 4];
  float4 F1, F2, G;
  {
    float t, mL;
    t = s1v.x + m2; mL = fmaxf(t, ALPHA * t);
    F1.x = __builtin_amdgcn_exp2f(s1v.x - mL);
    F2.x = __builtin_amdgcn_exp2f(fmaf(ALPHA, s1v.x, -mL));
    G.x  = __builtin_amdgcn_exp2f(-s1v.x);
    t = s1v.y + m2; mL = fmaxf(t, ALPHA * t);
    F1.y = __builtin_amdgcn_exp2f(s1v.y - mL);
    F2.y = __builtin_amdgcn_exp2f(fmaf(ALPHA, s1v.y, -mL));
    G.y  = __builtin_amdgcn_exp2f(-s1v.y);
    t = s1v.z + m2; mL = fmaxf(t, ALPHA * t);
    F1.z = __builtin_amdgcn_exp2f(s1v.z - mL);
    F2.z = __builtin_amdgcn_exp2f(fmaf(ALPHA, s1v.z, -mL));
    G.z  = __builtin_amdgcn_exp2f(-s1v.z);
    t = s1v.w + m2; mL = fmaxf(t, ALPHA * t);
    F1.w = __builtin_amdgcn_exp2f(s1v.w - mL);
    F2.w = __builtin_amdgcn_exp2f(fmaf(ALPHA, s1v.w, -mL));
    G.w  = __builtin_amdgcn_exp2f(-s1v.w);
  }
  *(float4*)&g_F1[tid * 4] = F1;
  *(float4*)&g_F2[tid * 4] = F2;
  *(float4*)&g_G [tid * 4] = G;
}

// ---- kernel 3: rZ_i = 1 / sum_j P_ij (f32, select form). One wave per row. ----
__global__ __launch_bounds__(256) void k_z(){
  __shared__ __align__(16) float2 EL[KDIM];    // 32 KB
  const int tid = threadIdx.x;
  #pragma unroll
  for (int it = 0; it < 8; ++it)
    ((uint4*)EL)[it * 256 + tid] = ((const uint4*)g_E)[it * 256 + tid];
  __syncthreads();
  const int wid = tid >> 6, lane = tid & 63;
  const int row = blockIdx.x * 4 + wid;
  const float Gi = g_G[row], F1 = g_F1[row], F2 = g_F2[row];
  float z = 0.f;
  #pragma unroll 8
  for (int c = 0; c < 64; ++c){
    const float2 e = EL[c * 64 + lane];
    z += (e.x >= Gi) ? e.x * F1 : e.y * F2;
  }
  #pragma unroll
  for (int m = 32; m >= 1; m >>= 1) z += __shfl_xor(z, m, 64);
  if (lane == 0) g_rZ[row] = 1.0f / z;
}

// ---- kernel 4: transpose+convert x (f32, j-major) -> g_xT (f16, n-major). ----
__global__ __launch_bounds__(256) void k_transpose(const float* __restrict__ x){
  __shared__ __align__(16) unsigned short T[64][80];  // 160B rows: 16B-aligned
  const int n0 = blockIdx.x * 64, j0 = blockIdx.y * 64;
  const int tid = threadIdx.x;
  #pragma unroll
  for (int it = 0; it < 4; ++it){
    const int idx = it * 256 + tid;
    const int r = idx >> 4, c4 = idx & 15;
    float4 v = *(const float4*)(x + (size_t)(j0 + r) * NDIM + n0 + c4 * 4);
    T[c4 * 4 + 0][r] = f2h(v.x);
    T[c4 * 4 + 1][r] = f2h(v.y);
    T[c4 * 4 + 2][r] = f2h(v.z);
    T[c4 * 4 + 3][r] = f2h(v.w);
  }
  __syncthreads();
  #pragma unroll
  for (int it = 0; it < 2; ++it){
    const int idx = it * 256 + tid;
    const int n = idx >> 3, cb = idx & 7;
    uint4 u = *(const uint4*)&T[n][cb * 8];
    *(uint4*)(g_xT + (size_t)(n0 + n) * KDIM + j0 + cb * 8) = u;
  }
}

// ---- kernel 5: h = (P @ x) * rZ with A = P generated in-register. ----
// M=4096 N=1024 K=4096. 128x128 tile, BK=64, 512 threads = 8 waves stacked in m
// (wave-tile 16m x 128n, nf=8) so every A element is computed exactly once/block.
// Only B (xT) staged via glds (XOR bank swizzle); E1/E2 resident in LDS (32 KB).
// Double-buffered B, ONE barrier per K-iter (prefetch before compute).
__global__ __launch_bounds__(512, 2) void k_gemm(float* __restrict__ out){
  __shared__ __align__(16) float EL2[2 * KDIM];        // 32 KB (E1,E2 interleaved)
  __shared__ __align__(16) unsigned short Bb[2][8192]; // 2 x 16 KB (f16)
  const int tid  = threadIdx.x;
  const int w    = tid >> 6, lane = tid & 63;
  const int quad = lane >> 4, l15 = lane & 15;
  const int i0 = blockIdx.y * 128, n0 = blockIdx.x * 128;
  const int arow = i0 + w * 16 + l15;                  // this lane's A row
  const float Gi  = g_G [arow];
  const float F1i = g_F1[arow];
  const float F2i = g_F2[arow];
  const int srow = lane >> 3, sblk = (lane & 7) ^ srow;

  // E1/E2 -> LDS once (read-only afterwards; first loop barrier orders it)
  #pragma unroll
  for (int it = 0; it < 4; ++it)
    ((uint4*)EL2)[it * 512 + tid] = ((const uint4*)g_E)[it * 512 + tid];

  f32x4 acc[8] = {};

  auto stage = [&](int kt, int buf){
    const int kbase = kt * 64;
    #pragma unroll
    for (int c = 0; c < 2; ++c){
      const int ca = (w << 1) + c;                     // chunk 0..15 (8 n-rows each)
      const int r  = ca * 8 + srow;
      const unsigned short* gb = g_xT + (size_t)(n0 + r) * KDIM + kbase + sblk * 8;
      __builtin_amdgcn_global_load_lds((const __attribute__((address_space(1))) void*)gb,
          (__attribute__((address_space(3))) void*)(&Bb[buf][ca * 512]), 16, 0, 0);
    }
  };

  stage(0, 0);
  for (int kt = 0; kt < 64; ++kt){
    __syncthreads();
    if (kt + 1 < 64) stage(kt + 1, (kt + 1) & 1);
    const int buf = kt & 1;
    #pragma unroll
    for (int ks = 0; ks < 2; ++ks){
      const int k0 = kt * 64 + ks * 32 + quad * 8;     // 8 k-values for this lane
      const float4* Ek4 = (const float4*)(EL2 + 2 * k0);
      union { fp16x2 h[4]; f16x8 v; } af;
      #pragma unroll
      for (int jp = 0; jp < 4; ++jp){
        const float4 e = Ek4[jp];                      // (E1,E2,E1,E2) for 2 ks
        const bool sa = e.x >= Gi, sb = e.z >= Gi;
        const float pa = (sa ? e.x : e.y) * (sa ? F1i : F2i);
        const float pb = (sb ? e.z : e.w) * (sb ? F1i : F2i);
        af.h[jp] = __builtin_amdgcn_cvt_pkrtz(pa, pb);
      }
      #pragma unroll
      for (int nf = 0; nf < 8; ++nf){
        const int n = nf * 16 + l15;
        const int lbq = ((ks << 2) + quad) ^ (n & 7);  // XOR-deswizzle k-block
        const f16x8 bfr = *(const f16x8*)((const char*)&Bb[buf][0] + n * 128 + lbq * 16);
        acc[nf] = __builtin_amdgcn_mfma_f32_16x16x32_f16(af.v, bfr, acc[nf], 0, 0, 0);
      }
    }
  }

  // epilogue: scale by 1/Z_i. C/D layout: col=lane&15, row=quad*4+reg.
  #pragma unroll
  for (int r = 0; r < 4; ++r){
    const int orow = i0 + w * 16 + quad * 4 + r;
    const float rz = g_rZ[orow];
    #pragma unroll
    for (int nf = 0; nf < 8; ++nf)
      out[(size_t)orow * NDIM + n0 + nf * 16 + l15] = acc[nf][r] * rz;
  }
}

extern "C" void kernel_launch(void* const* d_in, const int* in_sizes, int n_in,
                              void* d_out, int out_size, void* d_ws, size_t ws_size,
                              hipStream_t stream){
  const float* x = (const float*)d_in[0];   // f32 (4096x1024)
  const float* w = (const float*)d_in[1];   // f32 (2048)
  float* out = (float*)d_out;               // f32 (4096x1024)
  (void)in_sizes; (void)n_in; (void)out_size; (void)d_ws; (void)ws_size;

  k_dots     <<<dim3(1024),   dim3(256),  0, stream>>>(x, w);
  k_escan    <<<dim3(1),      dim3(1024), 0, stream>>>();
  k_z        <<<dim3(1024),   dim3(256),  0, stream>>>();
  k_transpose<<<dim3(16, 64), dim3(256),  0, stream>>>(x);
  k_gemm     <<<dim3(8, 32),  dim3(512),  0, stream>>>(out);
}